// Round 4
// baseline (3017.590 us; speedup 1.0000x reference)
//
#include <hip/hip_runtime.h>
#include <hip/hip_fp16.h>
#include <cstdint>

typedef _Float16 f16x8 __attribute__((ext_vector_type(8)));
typedef _Float16 half2_t __attribute__((ext_vector_type(2)));
typedef float f32x4 __attribute__((ext_vector_type(4)));
typedef uint32_t u32x4 __attribute__((ext_vector_type(4)));
typedef uint32_t u32x2 __attribute__((ext_vector_type(2)));

// Sizes: B=64, T=1024, IN=256, HID=256. Gate column c = 4u + gi (u=unit, gi: 0=i,1=f,2=o,3=c).
// Weight K-pair row kp in [0,128) packs Wh rows 2kp,2kp+1 (pairs h units 2kp,2kp+1).
// Rows 0..111 (28 quads) -> registers (named u32x4). Rows 112..127 (4 quads) -> LDS.

// Workspace layout (bytes)
#define XG_OFF    0ULL
#define XG_BYTES  134217728ULL   // xg[b*1024+t][c] fp16, plain row-major
#define AP_OFF    (XG_OFF + XG_BYTES)
#define AP_BYTES  33554432ULL
#define BP_OFF    (AP_OFF + AP_BYTES)
#define BP_BYTES  524288ULL
#define WQ_OFF    (BP_OFF + BP_BYTES)
#define WQ_BYTES  458752ULL      // [28 q][256 u][4 gi][4 i] u32
#define WT_OFF    (WQ_OFF + WQ_BYTES)
#define WT_BYTES  65536ULL       // [4 qt][256 u][4 slot][4 i] u32, slot = gi^(u&3) (pre-swizzled)
#define BIAS_OFF  (WT_OFF + WT_BYTES)

__device__ inline half2_t u2h2(uint32_t v) {
    union { uint32_t u; half2_t h; } c; c.u = v; return c.h;
}
#define FD(W, H, A) __builtin_amdgcn_fdot2(u2h2(W), u2h2(H), (A), false)

#define GI4(F, q) F(q,0) F(q,1) F(q,2) F(q,3)
#define QALL(F) GI4(F,0) GI4(F,1) GI4(F,2) GI4(F,3) GI4(F,4) GI4(F,5) GI4(F,6) \
  GI4(F,7) GI4(F,8) GI4(F,9) GI4(F,10) GI4(F,11) GI4(F,12) GI4(F,13) GI4(F,14) \
  GI4(F,15) GI4(F,16) GI4(F,17) GI4(F,18) GI4(F,19) GI4(F,20) GI4(F,21) GI4(F,22) \
  GI4(F,23) GI4(F,24) GI4(F,25) GI4(F,26) GI4(F,27)
#define QALL_Q(F) F(0) F(1) F(2) F(3) F(4) F(5) F(6) F(7) F(8) F(9) F(10) F(11) F(12) \
  F(13) F(14) F(15) F(16) F(17) F(18) F(19) F(20) F(21) F(22) F(23) F(24) F(25) F(26) F(27)

// ---------------- Phase 0: pack weights + B frags + bias ----------------
__global__ void pack_weights(const float* __restrict__ Wi, const float* __restrict__ Wf,
                             const float* __restrict__ Wo, const float* __restrict__ Wc,
                             const float* __restrict__ bi, const float* __restrict__ bf,
                             const float* __restrict__ bo, const float* __restrict__ bc,
                             uint32_t* __restrict__ WQg, uint32_t* __restrict__ WTg,
                             __half* __restrict__ Bp, float* __restrict__ bias_eff)
{
    int tidg = blockIdx.x * blockDim.x + threadIdx.x;
    if (tidg < 114688) {
        // WQg[((q*256+u)*4+gi)*4+i] = pack(W_gi[2kp][u], W_gi[2kp+1][u]), kp = q*4+i
        int i  = tidg & 3;
        int gi = (tidg >> 2) & 3;
        int u  = (tidg >> 4) & 255;
        int q  = tidg >> 12;
        int kp = q * 4 + i;
        const float* W = (gi == 0) ? Wi : (gi == 1) ? Wf : (gi == 2) ? Wo : Wc;
        union { uint32_t u32; __half h[2]; } pk;
        pk.h[0] = __float2half(W[(2 * kp) * 256 + u]);
        pk.h[1] = __float2half(W[(2 * kp + 1) * 256 + u]);
        WQg[tidg] = pk.u32;
    } else if (tidg < 131072) {
        // tail, pre-swizzled: slot = gi ^ (u&3); kp = 112 + qt*4 + i
        int e  = tidg - 114688;
        int i  = e & 3;
        int sl = (e >> 2) & 3;
        int u  = (e >> 4) & 255;
        int qt = e >> 12;
        int gi = sl ^ (u & 3);
        int kp = 112 + qt * 4 + i;
        const float* W = (gi == 0) ? Wi : (gi == 1) ? Wf : (gi == 2) ? Wo : Wc;
        union { uint32_t u32; __half h[2]; } pk;
        pk.h[0] = __float2half(W[(2 * kp) * 256 + u]);
        pk.h[1] = __float2half(W[(2 * kp + 1) * 256 + u]);
        WTg[e] = pk.u32;
    } else if (tidg < 131072 + 262144) {
        // Bp[((n*8+kk)*64+l)*8+i] = Wx_eff[k = kk*32+(l>>4)*8+i][c = n*16+(l&15)]
        int beta = tidg - 131072;
        int i = beta & 7;
        int l = (beta >> 3) & 63;
        int kk = (beta >> 9) & 7;
        int n = beta >> 12;
        int c = n * 16 + (l & 15);
        int u = c >> 2, g = c & 3;
        int k = kk * 32 + (l >> 4) * 8 + i;
        const float* W = (g == 0) ? Wi : (g == 1) ? Wf : (g == 2) ? Wo : Wc;
        Bp[beta] = __float2half(W[(256 + k) * 256 + u]);
    } else if (tidg < 131072 + 262144 + 1024) {
        int c = tidg - (131072 + 262144);
        int g = c & 3;
        const float* bb = (g == 0) ? bi : (g == 1) ? bf : (g == 2) ? bo : bc;
        bias_eff[c] = bb[c >> 2];
    }
}

// ---------------- Phase 0b: pack x into A fragments ----------------
__global__ void pack_a(const float* __restrict__ x, __half* __restrict__ Ap)
{
    int t = blockIdx.x * blockDim.x + threadIdx.x;
    int l  = t & 63;
    int kk = (t >> 6) & 7;
    int m  = t >> 9;
    int row = m * 16 + (l & 15);
    int k0  = kk * 32 + (l >> 4) * 8;
    const float* src = x + (size_t)row * 256 + k0;
    f16x8 v;
#pragma unroll
    for (int i = 0; i < 8; ++i) v[i] = (_Float16)src[i];
    *reinterpret_cast<f16x8*>(Ap + (size_t)t * 8) = v;
}

// ---------------- Phase 1: xg = x @ Wx + bias (plain row-major fp16 out) ----------------
__global__ __launch_bounds__(256) void gemm_xg(const __half* __restrict__ Ap,
                                               const __half* __restrict__ Bp,
                                               const float* __restrict__ bias_eff,
                                               __half* __restrict__ xgh)
{
    int wave = threadIdx.x >> 6;
    int lane = threadIdx.x & 63;
    int mtile = blockIdx.x * 4 + wave;
    int ntbase = blockIdx.y * 16;

    f16x8 a[8];
#pragma unroll
    for (int kk = 0; kk < 8; ++kk)
        a[kk] = *reinterpret_cast<const f16x8*>(Ap + ((size_t)(mtile * 8 + kk) * 64 + lane) * 8);

    int col_lo = lane & 15;
    int rgrp = lane >> 4;
#pragma unroll 1
    for (int j = 0; j < 16; ++j) {
        int nt = ntbase + j;
        int c = nt * 16 + col_lo;
        float bb = bias_eff[c];
        f32x4 acc = {bb, bb, bb, bb};
#pragma unroll
        for (int kk = 0; kk < 8; ++kk) {
            f16x8 bfr = *reinterpret_cast<const f16x8*>(Bp + ((size_t)(nt * 8 + kk) * 64 + lane) * 8);
            acc = __builtin_amdgcn_mfma_f32_16x16x32_f16(a[kk], bfr, acc, 0, 0, 0);
        }
#pragma unroll
        for (int r = 0; r < 4; ++r) {
            int row = mtile * 16 + rgrp * 4 + r;
            xgh[(size_t)row * 1024 + c] = __float2half(acc[r]);
        }
    }
}

// ---------------- Phase 2: recurrence. 64 WGs x 256 threads, thread = one unit ---------
// 4 waves = 1 wave/SIMD -> unified reg budget 512/wave. Thread u owns cols 4u..4u+3:
// 448 weight u32 in 112 named u32x4 (arch+AGPR), 64 u32 tail in LDS. No cross-lane ops.
__global__ __attribute__((amdgpu_flat_work_group_size(256, 256), amdgpu_waves_per_eu(1, 1)))
void lstm_rec(const __half* __restrict__ xg,
              const uint32_t* __restrict__ WQg,
              const uint32_t* __restrict__ WTg,
              float* __restrict__ out)
{
    const int b = blockIdx.x;
    const int u = threadIdx.x;

    __shared__ uint32_t WT[16384];                // 64 KB tail weights (pre-swizzled)
    __shared__ alignas(16) uint32_t h2[2][128];   // packed-f16 h, double-buffered

    for (int i = u; i < 4096; i += 256)
        reinterpret_cast<u32x4*>(WT)[i] = reinterpret_cast<const u32x4*>(WTg)[i];
    if (u < 128) { h2[0][u] = 0u; h2[1][u] = 0u; }

    // ---- 112 named register quads ----
#define DECLW(q, gi) u32x4 w_##q##_##gi;
    QALL(DECLW)
#undef DECLW
#define LOADW(q, gi) \
    w_##q##_##gi = *reinterpret_cast<const u32x4*>(WQg + ((((q) * 256) + u) * 4 + (gi)) * 4);
    QALL(LOADW)
#undef LOADW
    __syncthreads();

    const int m3 = u & 3;
    const int s0 = (0 ^ m3) * 4, s1 = (1 ^ m3) * 4, s2 = (2 ^ m3) * 4, s3 = (3 ^ m3) * 4;

    float cst = 0.f;
    const __half* xrow = xg + (size_t)b * 1024 * 1024 + 4 * u;
    u32x2 xw = *reinterpret_cast<const u32x2*>(xrow);   // 1-step-ahead prefetch

    for (int t = 0; t < 1024; ++t) {
        const uint32_t* hr = h2[t & 1];
        int tn = (t < 1023) ? (t + 1) : 1023;
        u32x2 xw_next = *reinterpret_cast<const u32x2*>(xrow + (size_t)tn * 1024);

        float a0 = 0.f, a1 = 0.f, a2 = 0.f, a3 = 0.f;
#define DOTW(q, gi) \
        a##gi = FD(w_##q##_##gi[0], hq[0], a##gi); \
        a##gi = FD(w_##q##_##gi[1], hq[1], a##gi); \
        a##gi = FD(w_##q##_##gi[2], hq[2], a##gi); \
        a##gi = FD(w_##q##_##gi[3], hq[3], a##gi);
#define DOTQ(q) { \
        u32x4 hq = *reinterpret_cast<const u32x4*>(hr + (q) * 4); \
        DOTW(q, 0) DOTW(q, 1) DOTW(q, 2) DOTW(q, 3) }
        QALL_Q(DOTQ)
#undef DOTQ
#undef DOTW

        // tail rows 112..127 from LDS (XOR-swizzled slots, conflict-free b128)
#define TAILQ(qt) { \
        u32x4 hq = *reinterpret_cast<const u32x4*>(hr + 112 + (qt) * 4); \
        const uint32_t* tb = &WT[(((qt) * 256 + u) * 4) * 4]; \
        u32x4 wt0 = *reinterpret_cast<const u32x4*>(tb + s0); \
        u32x4 wt1 = *reinterpret_cast<const u32x4*>(tb + s1); \
        u32x4 wt2 = *reinterpret_cast<const u32x4*>(tb + s2); \
        u32x4 wt3 = *reinterpret_cast<const u32x4*>(tb + s3); \
        a0 = FD(wt0[0], hq[0], a0); a0 = FD(wt0[1], hq[1], a0); \
        a0 = FD(wt0[2], hq[2], a0); a0 = FD(wt0[3], hq[3], a0); \
        a1 = FD(wt1[0], hq[0], a1); a1 = FD(wt1[1], hq[1], a1); \
        a1 = FD(wt1[2], hq[2], a1); a1 = FD(wt1[3], hq[3], a1); \
        a2 = FD(wt2[0], hq[0], a2); a2 = FD(wt2[1], hq[1], a2); \
        a2 = FD(wt2[2], hq[2], a2); a2 = FD(wt2[3], hq[3], a2); \
        a3 = FD(wt3[0], hq[0], a3); a3 = FD(wt3[1], hq[1], a3); \
        a3 = FD(wt3[2], hq[2], a3); a3 = FD(wt3[3], hq[3], a3); }
        TAILQ(0) TAILQ(1) TAILQ(2) TAILQ(3)
#undef TAILQ

        union { u32x2 v; __half h[4]; } xc; xc.v = xw;
        float pre0 = a0 + __half2float(xc.h[0]);
        float pre1 = a1 + __half2float(xc.h[1]);
        float pre2 = a2 + __half2float(xc.h[2]);
        float pre3 = a3 + __half2float(xc.h[3]);

        float ig = __builtin_amdgcn_rcpf(1.f + __builtin_amdgcn_exp2f(-1.44269504f * pre0));
        float fg = __builtin_amdgcn_rcpf(1.f + __builtin_amdgcn_exp2f(-1.44269504f * pre1));
        float og = __builtin_amdgcn_rcpf(1.f + __builtin_amdgcn_exp2f(-1.44269504f * pre2));
        float cg = fmaf(-2.f, __builtin_amdgcn_rcpf(1.f + __builtin_amdgcn_exp2f(2.88539008f * pre3)), 1.f);

        cst = fmaf(fg, cst, ig * cg);
        float th = fmaf(-2.f, __builtin_amdgcn_rcpf(1.f + __builtin_amdgcn_exp2f(2.88539008f * cst)), 1.f);
        float hv = og * th;

        out[((size_t)t * 64 + b) * 256 + u] = hv;
        reinterpret_cast<__half*>(h2[(t + 1) & 1])[u] = __float2half(hv);
        __syncthreads();
        xw = xw_next;
    }
}

// ---------------- launch ----------------
extern "C" void kernel_launch(void* const* d_in, const int* in_sizes, int n_in,
                              void* d_out, int out_size, void* d_ws, size_t ws_size,
                              hipStream_t stream)
{
    const float* x  = (const float*)d_in[0];
    const float* Wi = (const float*)d_in[1];
    const float* bi = (const float*)d_in[2];
    const float* Wf = (const float*)d_in[3];
    const float* bf = (const float*)d_in[4];
    const float* Wo = (const float*)d_in[5];
    const float* bo = (const float*)d_in[6];
    const float* Wc = (const float*)d_in[7];
    const float* bc = (const float*)d_in[8];

    char* ws = (char*)d_ws;
    __half*   xgh      = (__half*)(ws + XG_OFF);
    __half*   Ap       = (__half*)(ws + AP_OFF);
    __half*   Bp       = (__half*)(ws + BP_OFF);
    uint32_t* WQg      = (uint32_t*)(ws + WQ_OFF);
    uint32_t* WTg      = (uint32_t*)(ws + WT_OFF);
    float*    bias_eff = (float*)(ws + BIAS_OFF);

    pack_weights<<<1540, 256, 0, stream>>>(Wi, Wf, Wo, Wc, bi, bf, bo, bc, WQg, WTg, Bp, bias_eff);
    pack_a<<<8192, 256, 0, stream>>>(x, Ap);
    gemm_xg<<<dim3(1024, 4), 256, 0, stream>>>(Ap, Bp, bias_eff, xgh);
    lstm_rec<<<64, 256, 0, stream>>>(xgh, WQg, WTg, (float*)d_out);
}